// Round 4
// baseline (267.844 us; speedup 1.0000x reference)
//
#include <hip/hip_runtime.h>
#include <hip/hip_bf16.h>
#include <cmath>

typedef unsigned short u16;
typedef __attribute__((ext_vector_type(8))) short s8v;    // 8 x bf16 bits
typedef __attribute__((ext_vector_type(4))) float f4v;
typedef __attribute__((ext_vector_type(4))) unsigned short u16x4;

#define MFMA(a,b,c) __builtin_amdgcn_mfma_f32_16x16x32_bf16((a),(b),(c),0,0,0)

__device__ __forceinline__ u16 f2bf(float f) {
    union { float f; unsigned i; } x; x.f = f;
    unsigned r = x.i + 0x7FFFu + ((x.i >> 16) & 1u);
    return (u16)(r >> 16);
}
__device__ __forceinline__ unsigned cvtpk(float lo, float hi) {
    unsigned r;
    asm("v_cvt_pk_bf16_f32 %0, %1, %2" : "=v"(r) : "v"(lo), "v"(hi));
    return r;
}

// ---------------------------------------------------------------------------
// Kernel 1: fused QKV projection (f32 in -> bf16 MFMA -> bf16 out).
// Q output is PRESCALED by 0.125*log2(e) so attn uses exp2 directly.
// Q,K stored [b][h][T][d]; V stored transposed as VT [b][h][d][T].
// ---------------------------------------------------------------------------
__global__ __launch_bounds__(256)
void qkv_proj(const float* __restrict__ q, const float* __restrict__ kv,
              const float* __restrict__ Wq, const float* __restrict__ bq,
              const float* __restrict__ Wkv, const float* __restrict__ bkv,
              u16* __restrict__ QH, u16* __restrict__ KH, u16* __restrict__ VT)
{
    __shared__ u16 Al[128][40];   // [m][k]
    __shared__ u16 Bl[128][40];   // [n][k]

    const int bid = blockIdx.x;
    const int mt = bid / 12, nt = bid - mt * 12;
    const int m0 = mt << 7, n0 = nt << 7;

    const int tid  = threadIdx.x;
    const int lane = tid & 63;
    const int w    = tid >> 6;
    const int wr = (w >> 1) * 64, wc = (w & 1) * 64;
    const int cl = lane & 15, rl = lane >> 4;

    const int bb  = m0 >> 11;
    const int t0  = m0 & 2047;
    const int vv  = t0 >> 8;
    const int hw0 = t0 & 255;

    const float* Abase = ((nt < 4) ? q : kv) + (size_t)(vv * 4 + bb) * 131072 + hw0;

    const float* W; const float* bias; int NW, wn0, dn0; u16* dst;
    if (nt < 4)      { W = Wq;  bias = bq;  NW = 512;  wn0 = n0;       dn0 = n0;        dst = QH; }
    else if (nt < 8) { W = Wkv; bias = bkv; NW = 1024; wn0 = n0 - 512; dn0 = n0 - 512;  dst = KH; }
    else             { W = Wkv; bias = bkv; NW = 1024; wn0 = n0 - 512; dn0 = n0 - 1024; dst = VT; }

    const float oscale = (nt < 4) ? 0.18033688011f : 1.0f;  // 0.125*log2(e) for Q

    f4v acc[4][4] = {};

    const int lk = tid >> 3;          // k within tile: 0..31
    const int lg = (tid & 7) * 16;    // m/n group base

    for (int k0 = 0; k0 < 512; k0 += 32) {
        {   // A tile: f32 global contiguous along m (hw), cvt+transpose-on-write
            const float* g = Abase + (size_t)(k0 + lk) * 256 + lg;
            #pragma unroll
            for (int u = 0; u < 4; ++u) {
                f4v v = *reinterpret_cast<const f4v*>(g + u * 4);
                unsigned w0 = cvtpk(v[0], v[1]);
                unsigned w1 = cvtpk(v[2], v[3]);
                Al[lg + u * 4 + 0][lk] = (u16)w0;
                Al[lg + u * 4 + 1][lk] = (u16)(w0 >> 16);
                Al[lg + u * 4 + 2][lk] = (u16)w1;
                Al[lg + u * 4 + 3][lk] = (u16)(w1 >> 16);
            }
        }
        {   // B tile
            const float* g = W + (size_t)(k0 + lk) * NW + wn0 + lg;
            #pragma unroll
            for (int u = 0; u < 4; ++u) {
                f4v v = *reinterpret_cast<const f4v*>(g + u * 4);
                unsigned w0 = cvtpk(v[0], v[1]);
                unsigned w1 = cvtpk(v[2], v[3]);
                Bl[lg + u * 4 + 0][lk] = (u16)w0;
                Bl[lg + u * 4 + 1][lk] = (u16)(w0 >> 16);
                Bl[lg + u * 4 + 2][lk] = (u16)w1;
                Bl[lg + u * 4 + 3][lk] = (u16)(w1 >> 16);
            }
        }
        __syncthreads();
        s8v af[4], bf[4];
        #pragma unroll
        for (int mi = 0; mi < 4; ++mi)
            af[mi] = *reinterpret_cast<const s8v*>(&Al[wr + mi * 16 + cl][rl * 8]);
        #pragma unroll
        for (int ni = 0; ni < 4; ++ni)
            bf[ni] = *reinterpret_cast<const s8v*>(&Bl[wc + ni * 16 + cl][rl * 8]);
        #pragma unroll
        for (int mi = 0; mi < 4; ++mi)
            #pragma unroll
            for (int ni = 0; ni < 4; ++ni)
                acc[mi][ni] = MFMA(af[mi], bf[ni], acc[mi][ni]);
        __syncthreads();
    }

    if (nt < 8) {
        #pragma unroll
        for (int ni = 0; ni < 4; ++ni) {
            const int nl   = wc + ni * 16 + cl;
            const float bv = bias[wn0 + nl];
            const int cout = dn0 + nl;
            const int hh = cout >> 6, dd = cout & 63;
            const size_t obase = ((size_t)(bb * 8 + hh) * 2048) * 64 + dd;
            #pragma unroll
            for (int mi = 0; mi < 4; ++mi)
                #pragma unroll
                for (int r = 0; r < 4; ++r) {
                    const int m = m0 + wr + mi * 16 + rl * 4 + r;
                    const int t = m & 2047;
                    dst[obase + (size_t)t * 64] = f2bf((acc[mi][ni][r] + bv) * oscale);
                }
        }
    } else {
        // V: store transposed VT[b][h][d][T], 4 consecutive tokens -> 8B store
        #pragma unroll
        for (int ni = 0; ni < 4; ++ni) {
            const int nl   = wc + ni * 16 + cl;
            const float bv = bias[wn0 + nl];
            const int cout = dn0 + nl;
            const int hh = cout >> 6, dd = cout & 63;
            const size_t obase = ((size_t)(bb * 8 + hh) * 64 + dd) * 2048;
            #pragma unroll
            for (int mi = 0; mi < 4; ++mi) {
                const int m = m0 + wr + mi * 16 + rl * 4;
                const int t = m & 2047;
                u16x4 pk;
                #pragma unroll
                for (int r = 0; r < 4; ++r) pk[r] = f2bf(acc[mi][ni][r] + bv);
                *reinterpret_cast<u16x4*>(dst + obase + t) = pk;
            }
        }
    }
}

// ---------------------------------------------------------------------------
// Kernel 2: block-causal flash attention. 1 wave = 16 q-rows (4096 WGs,
// 16 waves/CU). XCD-aware mapping: idx&7 = XCD, each XCD owns 4 bh values
// (2 MB K+VT working set -> L2-resident). No barriers. Q prescaled, exp2
// direct, cvt_pk P-store, double-buffered Pl.
// ---------------------------------------------------------------------------
__global__ __launch_bounds__(64)
void attn(const u16* __restrict__ QH, const u16* __restrict__ KH,
          const u16* __restrict__ VT, u16* __restrict__ YH)
{
    __shared__ u16 Pl[2][16][132];

    const int idx = blockIdx.x;
    const int g = idx & 7;                // XCD (round-robin dispatch)
    const int j = idx >> 3;               // 0..511 within XCD
    const int qg = 127 - (j >> 2);        // heavy q-groups first
    const int bh = g * 4 + (j & 3);       // 4 bh per XCD
    const int b = bh >> 3, h = bh & 7;
    const int lane = threadIdx.x;
    const int cl = lane & 15, rl = lane >> 4;
    const int nkt = ((qg >> 4) + 1) * 2;  // key tiles of 128 (block-causal)

    const u16* Qb = QH + (size_t)bh * 131072;
    const u16* Kb = KH + (size_t)bh * 131072;
    const u16* Vb = VT + (size_t)bh * 131072;

    const int qrow0 = qg * 16;

    s8v qf[2];
    #pragma unroll
    for (int kf = 0; kf < 2; ++kf)
        qf[kf] = *reinterpret_cast<const s8v*>(
            Qb + (size_t)(qrow0 + cl) * 64 + kf * 32 + rl * 8);

    f4v o[4] = {};
    float mrun[4], lp[4];
    #pragma unroll
    for (int i = 0; i < 4; ++i) { mrun[i] = -1e30f; lp[i] = 0.f; }

    for (int kt = 0; kt < nkt; ++kt) {
        const int kb0 = kt * 128;
        const int buf = kt & 1;

        // S = Q K^T (K fragments direct from L2-resident KH)
        f4v sc[8] = {};
        #pragma unroll
        for (int ni = 0; ni < 8; ++ni)
            #pragma unroll
            for (int kf = 0; kf < 2; ++kf) {
                s8v kfr = *reinterpret_cast<const s8v*>(
                    Kb + (size_t)(kb0 + ni * 16 + cl) * 64 + kf * 32 + rl * 8);
                sc[ni] = MFMA(qf[kf], kfr, sc[ni]);
            }

        // online softmax: row max across 16 col-lanes, exp2 direct
        float mn[4], al[4];
        #pragma unroll
        for (int r = 0; r < 4; ++r) {
            float rm = sc[0][r];
            #pragma unroll
            for (int ni = 1; ni < 8; ++ni) rm = fmaxf(rm, sc[ni][r]);
            rm = fmaxf(rm, __shfl_xor(rm, 1));
            rm = fmaxf(rm, __shfl_xor(rm, 2));
            rm = fmaxf(rm, __shfl_xor(rm, 4));
            rm = fmaxf(rm, __shfl_xor(rm, 8));
            mn[r] = fmaxf(mrun[r], rm);
            al[r] = exp2f(mrun[r] - mn[r]);
            mrun[r] = mn[r];
        }
        #pragma unroll
        for (int ni = 0; ni < 8; ++ni)
            #pragma unroll
            for (int r = 0; r < 4; ++r)
                sc[ni][r] = exp2f(sc[ni][r] - mn[r]);
        #pragma unroll
        for (int r = 0; r < 4; ++r) {
            float ps = sc[0][r];
            #pragma unroll
            for (int ni = 1; ni < 8; ++ni) ps += sc[ni][r];
            lp[r] = lp[r] * al[r] + ps;
        }
        #pragma unroll
        for (int di = 0; di < 4; ++di)
            #pragma unroll
            for (int r = 0; r < 4; ++r) o[di][r] *= al[r];

        // P -> LDS (bf16 via cvt_pk)
        #pragma unroll
        for (int ni = 0; ni < 8; ++ni) {
            const unsigned w0 = cvtpk(sc[ni][0], sc[ni][1]);
            const unsigned w1 = cvtpk(sc[ni][2], sc[ni][3]);
            const int col = ni * 16 + cl;
            Pl[buf][rl * 4 + 0][col] = (u16)w0;
            Pl[buf][rl * 4 + 1][col] = (u16)(w0 >> 16);
            Pl[buf][rl * 4 + 2][col] = (u16)w1;
            Pl[buf][rl * 4 + 3][col] = (u16)(w1 >> 16);
        }

        // PV: P (A-frags from LDS) x V^T (B-frags direct from L2-resident VT)
        #pragma unroll
        for (int kfr = 0; kfr < 4; ++kfr) {
            s8v pf = *reinterpret_cast<const s8v*>(&Pl[buf][cl][kfr * 32 + rl * 8]);
            #pragma unroll
            for (int di = 0; di < 4; ++di) {
                s8v vf = *reinterpret_cast<const s8v*>(
                    Vb + (size_t)(di * 16 + cl) * 2048 + kb0 + kfr * 32 + rl * 8);
                o[di] = MFMA(pf, vf, o[di]);
            }
        }
    }

    // normalize (row-sum reduce across col-lanes) and store Y [b][t][c]
    #pragma unroll
    for (int r = 0; r < 4; ++r) {
        float ls = lp[r];
        ls += __shfl_xor(ls, 1);
        ls += __shfl_xor(ls, 2);
        ls += __shfl_xor(ls, 4);
        ls += __shfl_xor(ls, 8);
        const float inv = 1.f / ls;
        const int t = qrow0 + rl * 4 + r;
        #pragma unroll
        for (int di = 0; di < 4; ++di) {
            const int c = h * 64 + di * 16 + cl;
            YH[((size_t)b * 2048 + t) * 512 + c] = f2bf(o[di][r] * inv);
        }
    }
}

// ---------------------------------------------------------------------------
// Kernel 3: output projection, computed transposed: C'[c][tok] = Wp^T . Y^T,
// so f32 stores are contiguous along hw of the v b c h w output layout.
// ---------------------------------------------------------------------------
__global__ __launch_bounds__(256)
void out_proj(const u16* __restrict__ YH, const float* __restrict__ Wp,
              const float* __restrict__ bp, float* __restrict__ out)
{
    __shared__ u16 Al[128][40];   // Wp^T tile: [cout][cin]
    __shared__ u16 Bl[128][40];   // Y tile: [token][cin]

    const int bid = blockIdx.x;
    const int ct = bid >> 6;
    const int mt = bid & 63;
    const int c0 = ct << 7, m0 = mt << 7;

    const int tid = threadIdx.x, lane = tid & 63, w = tid >> 6;
    const int wr = (w >> 1) * 64, wc = (w & 1) * 64;
    const int cl = lane & 15, rl = lane >> 4;

    f4v acc[4][4] = {};

    const int lk = tid >> 3;
    const int lg = (tid & 7) * 16;
    const int br = tid >> 2;
    const int bq4 = (tid & 3) * 8;

    for (int k0 = 0; k0 < 512; k0 += 32) {
        {   // A: Wp[k][c] f32 -> Al[c][k]
            const float* g = Wp + (size_t)(k0 + lk) * 512 + c0 + lg;
            #pragma unroll
            for (int u = 0; u < 4; ++u) {
                f4v v = *reinterpret_cast<const f4v*>(g + u * 4);
                unsigned w0 = cvtpk(v[0], v[1]);
                unsigned w1 = cvtpk(v[2], v[3]);
                Al[lg + u * 4 + 0][lk] = (u16)w0;
                Al[lg + u * 4 + 1][lk] = (u16)(w0 >> 16);
                Al[lg + u * 4 + 2][lk] = (u16)w1;
                Al[lg + u * 4 + 3][lk] = (u16)(w1 >> 16);
            }
        }
        #pragma unroll
        for (int it = 0; it < 2; ++it) {  // B: Y rows (bf16), linear b128
            const int row = br + it * 64;
            s8v v = *reinterpret_cast<const s8v*>(YH + (size_t)(m0 + row) * 512 + k0 + bq4);
            *reinterpret_cast<s8v*>(&Bl[row][bq4]) = v;
        }
        __syncthreads();
        s8v af[4], bfr[4];
        #pragma unroll
        for (int mi = 0; mi < 4; ++mi)
            af[mi] = *reinterpret_cast<const s8v*>(&Al[wr + mi * 16 + cl][rl * 8]);
        #pragma unroll
        for (int ni = 0; ni < 4; ++ni)
            bfr[ni] = *reinterpret_cast<const s8v*>(&Bl[wc + ni * 16 + cl][rl * 8]);
        #pragma unroll
        for (int mi = 0; mi < 4; ++mi)
            #pragma unroll
            for (int ni = 0; ni < 4; ++ni)
                acc[mi][ni] = MFMA(af[mi], bfr[ni], acc[mi][ni]);
        __syncthreads();
    }

    #pragma unroll
    for (int mi = 0; mi < 4; ++mi)
        #pragma unroll
        for (int r = 0; r < 4; ++r) {
            const int c = c0 + wr + mi * 16 + rl * 4 + r;   // D row = cout
            const float bv = bp[c];
            #pragma unroll
            for (int ni = 0; ni < 4; ++ni) {
                const int tok = m0 + wc + ni * 16 + cl;     // D col = token
                const int bb = tok >> 11, t = tok & 2047;
                const int vv = t >> 8, hw = t & 255;
                out[(size_t)(vv * 4 + bb) * 131072 + (size_t)c * 256 + hw] =
                    acc[mi][ni][r] + bv;
            }
        }
}

// ---------------------------------------------------------------------------
extern "C" void kernel_launch(void* const* d_in, const int* in_sizes, int n_in,
                              void* d_out, int out_size, void* d_ws, size_t ws_size,
                              hipStream_t stream)
{
    const float* q   = (const float*)d_in[0];
    const float* kv  = (const float*)d_in[1];
    const float* Wq  = (const float*)d_in[2];
    const float* bq  = (const float*)d_in[3];
    const float* Wkv = (const float*)d_in[4];
    const float* bkv = (const float*)d_in[5];
    const float* Wp  = (const float*)d_in[6];
    const float* bp  = (const float*)d_in[7];
    float* out = (float*)d_out;

    u16* ws = (u16*)d_ws;
    u16* QH = ws;                    // [4][8][2048][64] bf16 = 8 MB (prescaled)
    u16* KH = QH + 4194304;
    u16* VT = KH + 4194304;          // [4][8][64][2048] bf16 = 8 MB (transposed V)
    u16* YH = VT + 4194304;          // [4][2048][512] bf16 = 8 MB

    hipLaunchKernelGGL(qkv_proj, dim3(768), dim3(256), 0, stream,
                       q, kv, Wq, bq, Wkv, bkv, QH, KH, VT);
    hipLaunchKernelGGL(attn, dim3(4096), dim3(64), 0, stream, QH, KH, VT, YH);
    hipLaunchKernelGGL(out_proj, dim3(256), dim3(256), 0, stream, YH, Wp, bp, out);
}

// Round 5
// 191.366 us; speedup vs baseline: 1.3996x; 1.3996x over previous
//
#include <hip/hip_runtime.h>
#include <hip/hip_bf16.h>
#include <cmath>

typedef unsigned short u16;
typedef __attribute__((ext_vector_type(8))) short s8v;    // 8 x bf16 bits
typedef __attribute__((ext_vector_type(4))) float f4v;
typedef __attribute__((ext_vector_type(4))) unsigned short u16x4;

#define MFMA(a,b,c) __builtin_amdgcn_mfma_f32_16x16x32_bf16((a),(b),(c),0,0,0)

__device__ __forceinline__ float bf2f(u16 u) {
    union { float f; unsigned i; } x; x.i = ((unsigned)u) << 16; return x.f;
}
__device__ __forceinline__ u16 f2bf(float f) {
    union { float f; unsigned i; } x; x.f = f;
    unsigned r = x.i + 0x7FFFu + ((x.i >> 16) & 1u);
    return (u16)(r >> 16);
}
__device__ __forceinline__ unsigned cvtpk(float lo, float hi) {
    unsigned r;
    asm("v_cvt_pk_bf16_f32 %0, %1, %2" : "=v"(r) : "v"(lo), "v"(hi));
    return r;
}

// chunks-per-qblock and per-p-tile prefix (512-key chunks, block-causal)
__constant__ int CPER[8]  = {1,1,2,2,3,3,4,4};
__constant__ int POFF[17] = {0,1,2,3,4,6,8,10,12,15,18,21,24,28,32,36,40};

// ---------------------------------------------------------------------------
// Kernel 1: fused QKV projection (f32 in -> bf16 MFMA -> bf16 out).
// Q output PRESCALED by 0.125*log2(e). Q,K: [b][h][T][d]; V: VT [b][h][d][T].
// ---------------------------------------------------------------------------
__global__ __launch_bounds__(256)
void qkv_proj(const float* __restrict__ q, const float* __restrict__ kv,
              const float* __restrict__ Wq, const float* __restrict__ bq,
              const float* __restrict__ Wkv, const float* __restrict__ bkv,
              u16* __restrict__ QH, u16* __restrict__ KH, u16* __restrict__ VT)
{
    __shared__ u16 Al[128][40];
    __shared__ u16 Bl[128][40];

    const int bid = blockIdx.x;
    const int mt = bid / 12, nt = bid - mt * 12;
    const int m0 = mt << 7, n0 = nt << 7;

    const int tid  = threadIdx.x;
    const int lane = tid & 63;
    const int w    = tid >> 6;
    const int wr = (w >> 1) * 64, wc = (w & 1) * 64;
    const int cl = lane & 15, rl = lane >> 4;

    const int bb  = m0 >> 11;
    const int t0  = m0 & 2047;
    const int vv  = t0 >> 8;
    const int hw0 = t0 & 255;

    const float* Abase = ((nt < 4) ? q : kv) + (size_t)(vv * 4 + bb) * 131072 + hw0;

    const float* W; const float* bias; int NW, wn0, dn0; u16* dst;
    if (nt < 4)      { W = Wq;  bias = bq;  NW = 512;  wn0 = n0;       dn0 = n0;        dst = QH; }
    else if (nt < 8) { W = Wkv; bias = bkv; NW = 1024; wn0 = n0 - 512; dn0 = n0 - 512;  dst = KH; }
    else             { W = Wkv; bias = bkv; NW = 1024; wn0 = n0 - 512; dn0 = n0 - 1024; dst = VT; }

    const float oscale = (nt < 4) ? 0.18033688011f : 1.0f;  // 0.125*log2(e)

    f4v acc[4][4] = {};

    const int lk = tid >> 3;
    const int lg = (tid & 7) * 16;

    for (int k0 = 0; k0 < 512; k0 += 32) {
        {
            const float* g = Abase + (size_t)(k0 + lk) * 256 + lg;
            #pragma unroll
            for (int u = 0; u < 4; ++u) {
                f4v v = *reinterpret_cast<const f4v*>(g + u * 4);
                unsigned w0 = cvtpk(v[0], v[1]);
                unsigned w1 = cvtpk(v[2], v[3]);
                Al[lg + u * 4 + 0][lk] = (u16)w0;
                Al[lg + u * 4 + 1][lk] = (u16)(w0 >> 16);
                Al[lg + u * 4 + 2][lk] = (u16)w1;
                Al[lg + u * 4 + 3][lk] = (u16)(w1 >> 16);
            }
        }
        {
            const float* g = W + (size_t)(k0 + lk) * NW + wn0 + lg;
            #pragma unroll
            for (int u = 0; u < 4; ++u) {
                f4v v = *reinterpret_cast<const f4v*>(g + u * 4);
                unsigned w0 = cvtpk(v[0], v[1]);
                unsigned w1 = cvtpk(v[2], v[3]);
                Bl[lg + u * 4 + 0][lk] = (u16)w0;
                Bl[lg + u * 4 + 1][lk] = (u16)(w0 >> 16);
                Bl[lg + u * 4 + 2][lk] = (u16)w1;
                Bl[lg + u * 4 + 3][lk] = (u16)(w1 >> 16);
            }
        }
        __syncthreads();
        s8v af[4], bf[4];
        #pragma unroll
        for (int mi = 0; mi < 4; ++mi)
            af[mi] = *reinterpret_cast<const s8v*>(&Al[wr + mi * 16 + cl][rl * 8]);
        #pragma unroll
        for (int ni = 0; ni < 4; ++ni)
            bf[ni] = *reinterpret_cast<const s8v*>(&Bl[wc + ni * 16 + cl][rl * 8]);
        #pragma unroll
        for (int mi = 0; mi < 4; ++mi)
            #pragma unroll
            for (int ni = 0; ni < 4; ++ni)
                acc[mi][ni] = MFMA(af[mi], bf[ni], acc[mi][ni]);
        __syncthreads();
    }

    if (nt < 8) {
        #pragma unroll
        for (int ni = 0; ni < 4; ++ni) {
            const int nl   = wc + ni * 16 + cl;
            const float bv = bias[wn0 + nl];
            const int cout = dn0 + nl;
            const int hh = cout >> 6, dd = cout & 63;
            const size_t obase = ((size_t)(bb * 8 + hh) * 2048) * 64 + dd;
            #pragma unroll
            for (int mi = 0; mi < 4; ++mi)
                #pragma unroll
                for (int r = 0; r < 4; ++r) {
                    const int m = m0 + wr + mi * 16 + rl * 4 + r;
                    const int t = m & 2047;
                    dst[obase + (size_t)t * 64] = f2bf((acc[mi][ni][r] + bv) * oscale);
                }
        }
    } else {
        #pragma unroll
        for (int ni = 0; ni < 4; ++ni) {
            const int nl   = wc + ni * 16 + cl;
            const float bv = bias[wn0 + nl];
            const int cout = dn0 + nl;
            const int hh = cout >> 6, dd = cout & 63;
            const size_t obase = ((size_t)(bb * 8 + hh) * 64 + dd) * 2048;
            #pragma unroll
            for (int mi = 0; mi < 4; ++mi) {
                const int m = m0 + wr + mi * 16 + rl * 4;
                const int t = m & 2047;
                u16x4 pk;
                #pragma unroll
                for (int r = 0; r < 4; ++r) pk[r] = f2bf(acc[mi][ni][r] + bv);
                *reinterpret_cast<u16x4*>(dst + obase + t) = pk;
            }
        }
    }
}

// ---------------------------------------------------------------------------
// Kernel 2a: attention partials. WG = (bh, 128-row q-tile p, 512-key chunk c)
// -> 1280 uniform WGs x 4 waves. K/V tiles LDS-staged once per WG (batched
// reg-staging). Writes unnormalized-softmax partial (O/l bf16, m/l f32).
// ---------------------------------------------------------------------------
__global__ __launch_bounds__(256, 3)
void attn_part(const u16* __restrict__ QH, const u16* __restrict__ KH,
               const u16* __restrict__ VT,
               u16* __restrict__ Opart, float* __restrict__ ML)
{
    __shared__ u16 Kl[8192];        // [128 keys][64 d]
    __shared__ u16 Vl[8192];        // [64 d][128 keys]
    __shared__ u16 Pl[4][32][36];   // per-wave 32-key P slice

    const int wg = blockIdx.x;
    const int bh = wg & 31;
    const int s  = wg >> 5;               // 0..39 chunk slot within bh
    int p = 0;
    #pragma unroll
    for (int i = 0; i < 15; ++i) p += (s >= POFF[i + 1]) ? 1 : 0;
    const int c  = s - POFF[p];
    const int qb = p >> 1;
    const int kstart = c * 512;
    const int nk = min(512, (qb + 1) * 256 - kstart);
    const int nt128 = nk >> 7;            // 2 or 4 key tiles of 128

    const int tid = threadIdx.x, lane = tid & 63, w = tid >> 6;
    const int cl = lane & 15, rl = lane >> 4;

    const u16* Qb = QH + (size_t)bh * 131072;
    const u16* Kb = KH + (size_t)bh * 131072;
    const u16* Vb = VT + (size_t)bh * 131072;

    const int qrow0 = p * 128 + w * 32;

    s8v qf[2][2];
    #pragma unroll
    for (int mi = 0; mi < 2; ++mi)
        #pragma unroll
        for (int kf = 0; kf < 2; ++kf)
            qf[mi][kf] = *reinterpret_cast<const s8v*>(
                Qb + (size_t)(qrow0 + mi * 16 + cl) * 64 + kf * 32 + rl * 8);

    f4v o[2][4] = {};
    float mrun[8], lp[8];
    #pragma unroll
    for (int i = 0; i < 8; ++i) { mrun[i] = -1e30f; lp[i] = 0.f; }

    for (int kt = 0; kt < nt128; ++kt) {
        const int kb0 = kstart + kt * 128;

        // batched reg-staging of K tile (16KB) + V^T tile (16KB)
        s8v kst[4], vst[4];
        #pragma unroll
        for (int r = 0; r < 4; ++r) {
            const int f = r * 256 + tid;
            kst[r] = *reinterpret_cast<const s8v*>(Kb + (size_t)kb0 * 64 + f * 8);
            const int vrow = f >> 4, vch = f & 15;
            vst[r] = *reinterpret_cast<const s8v*>(
                Vb + (size_t)vrow * 2048 + kb0 + vch * 8);
        }
        #pragma unroll
        for (int r = 0; r < 4; ++r) {
            const int f = r * 256 + tid;
            *reinterpret_cast<s8v*>(&Kl[f * 8]) = kst[r];
            *reinterpret_cast<s8v*>(&Vl[f * 8]) = vst[r];
        }
        __syncthreads();

        // S = Q K^T (operands from LDS)
        f4v sc[2][8] = {};
        #pragma unroll
        for (int ni = 0; ni < 8; ++ni)
            #pragma unroll
            for (int kf = 0; kf < 2; ++kf) {
                s8v kfr = *reinterpret_cast<const s8v*>(
                    &Kl[(ni * 16 + cl) * 64 + kf * 32 + rl * 8]);
                sc[0][ni] = MFMA(qf[0][kf], kfr, sc[0][ni]);
                sc[1][ni] = MFMA(qf[1][kf], kfr, sc[1][ni]);
            }

        // online softmax (Q prescaled -> exp2 direct)
        float al[2][4];
        #pragma unroll
        for (int mi = 0; mi < 2; ++mi)
            #pragma unroll
            for (int r = 0; r < 4; ++r) {
                float rm = sc[mi][0][r];
                #pragma unroll
                for (int ni = 1; ni < 8; ++ni) rm = fmaxf(rm, sc[mi][ni][r]);
                rm = fmaxf(rm, __shfl_xor(rm, 1));
                rm = fmaxf(rm, __shfl_xor(rm, 2));
                rm = fmaxf(rm, __shfl_xor(rm, 4));
                rm = fmaxf(rm, __shfl_xor(rm, 8));
                const int idx = mi * 4 + r;
                const float mn = fmaxf(mrun[idx], rm);
                al[mi][r] = exp2f(mrun[idx] - mn);
                mrun[idx] = mn;
                float ps = 0.f;
                #pragma unroll
                for (int ni = 0; ni < 8; ++ni) {
                    sc[mi][ni][r] = exp2f(sc[mi][ni][r] - mn);
                    ps += sc[mi][ni][r];
                }
                lp[idx] = lp[idx] * al[mi][r] + ps;
            }
        #pragma unroll
        for (int mi = 0; mi < 2; ++mi)
            #pragma unroll
            for (int di = 0; di < 4; ++di)
                #pragma unroll
                for (int r = 0; r < 4; ++r) o[mi][di][r] *= al[mi][r];

        // PV in 32-key slices through per-wave LDS
        #pragma unroll
        for (int kfr = 0; kfr < 4; ++kfr) {
            #pragma unroll
            for (int mi = 0; mi < 2; ++mi)
                #pragma unroll
                for (int jj = 0; jj < 2; ++jj) {
                    const unsigned w0 = cvtpk(sc[mi][kfr * 2 + jj][0], sc[mi][kfr * 2 + jj][1]);
                    const unsigned w1 = cvtpk(sc[mi][kfr * 2 + jj][2], sc[mi][kfr * 2 + jj][3]);
                    const int col = jj * 16 + cl;
                    Pl[w][mi * 16 + rl * 4 + 0][col] = (u16)w0;
                    Pl[w][mi * 16 + rl * 4 + 1][col] = (u16)(w0 >> 16);
                    Pl[w][mi * 16 + rl * 4 + 2][col] = (u16)w1;
                    Pl[w][mi * 16 + rl * 4 + 3][col] = (u16)(w1 >> 16);
                }
            s8v pf0 = *reinterpret_cast<const s8v*>(&Pl[w][cl][rl * 8]);
            s8v pf1 = *reinterpret_cast<const s8v*>(&Pl[w][16 + cl][rl * 8]);
            #pragma unroll
            for (int di = 0; di < 4; ++di) {
                s8v vf = *reinterpret_cast<const s8v*>(
                    &Vl[(di * 16 + cl) * 128 + kfr * 32 + rl * 8]);
                o[0][di] = MFMA(pf0, vf, o[0][di]);
                o[1][di] = MFMA(pf1, vf, o[1][di]);
            }
        }
        __syncthreads();   // protect Kl/Vl before next stage
    }

    // write partial: Ohat = O/l (bf16), m & l (f32)
    const int slot = bh * 40 + POFF[p] + c;
    #pragma unroll
    for (int mi = 0; mi < 2; ++mi)
        #pragma unroll
        for (int r = 0; r < 4; ++r) {
            const int idx = mi * 4 + r;
            float ls = lp[idx];
            ls += __shfl_xor(ls, 1);
            ls += __shfl_xor(ls, 2);
            ls += __shfl_xor(ls, 4);
            ls += __shfl_xor(ls, 8);
            const float inv = 1.f / ls;
            const int rloc = w * 32 + mi * 16 + rl * 4 + r;
            if (cl == 0) {
                ML[(size_t)slot * 256 + rloc * 2 + 0] = mrun[idx];
                ML[(size_t)slot * 256 + rloc * 2 + 1] = ls;
            }
            #pragma unroll
            for (int di = 0; di < 4; ++di)
                Opart[(size_t)slot * 8192 + rloc * 64 + di * 16 + cl] =
                    f2bf(o[mi][di][r] * inv);
        }
}

// ---------------------------------------------------------------------------
// Kernel 2b: combine partials -> YH [b][t][c] bf16.
// WG = (bh, p-tile). 256 thr: row = t>>1, d-half = (t&1)*32.
// ---------------------------------------------------------------------------
__global__ __launch_bounds__(256)
void attn_combine(const u16* __restrict__ Opart, const float* __restrict__ ML,
                  u16* __restrict__ YH)
{
    const int wg = blockIdx.x;
    const int bh = wg & 31;
    const int p  = wg >> 5;
    const int b = bh >> 3, h = bh & 7;
    const int nc = CPER[p >> 1];
    const int sb = bh * 40 + POFF[p];

    const int t = threadIdx.x;
    const int rloc = t >> 1;
    const int dh = (t & 1) * 32;

    float mc[4], lc[4];
    float M = -1e30f;
    for (int c = 0; c < nc; ++c) {
        mc[c] = ML[(size_t)(sb + c) * 256 + rloc * 2 + 0];
        lc[c] = ML[(size_t)(sb + c) * 256 + rloc * 2 + 1];
        M = fmaxf(M, mc[c]);
    }
    float L = 0.f, wgt[4];
    for (int c = 0; c < nc; ++c) {
        wgt[c] = lc[c] * exp2f(mc[c] - M);
        L += wgt[c];
    }
    const float invL = 1.f / L;
    for (int c = 0; c < nc; ++c) wgt[c] *= invL;

    f4v a[8] = {};
    for (int c = 0; c < nc; ++c) {
        const float wv = wgt[c];
        #pragma unroll
        for (int u = 0; u < 4; ++u) {
            s8v vv = *reinterpret_cast<const s8v*>(
                &Opart[(size_t)(sb + c) * 8192 + rloc * 64 + dh + u * 8]);
            #pragma unroll
            for (int e = 0; e < 4; ++e) a[u * 2][e]     += wv * bf2f((u16)vv[e]);
            #pragma unroll
            for (int e = 0; e < 4; ++e) a[u * 2 + 1][e] += wv * bf2f((u16)vv[e + 4]);
        }
    }

    const size_t ybase = ((size_t)b * 2048 + p * 128 + rloc) * 512 + h * 64 + dh;
    #pragma unroll
    for (int u = 0; u < 4; ++u) {
        s8v ov;
        #pragma unroll
        for (int e = 0; e < 4; ++e) ov[e]     = (short)f2bf(a[u * 2][e]);
        #pragma unroll
        for (int e = 0; e < 4; ++e) ov[e + 4] = (short)f2bf(a[u * 2 + 1][e]);
        *reinterpret_cast<s8v*>(YH + ybase + u * 8) = ov;
    }
}

// ---------------------------------------------------------------------------
// Kernel 3: output projection (transposed): C'[c][tok] = Wp^T . Y^T.
// ---------------------------------------------------------------------------
__global__ __launch_bounds__(256)
void out_proj(const u16* __restrict__ YH, const float* __restrict__ Wp,
              const float* __restrict__ bp, float* __restrict__ out)
{
    __shared__ u16 Al[128][40];
    __shared__ u16 Bl[128][40];

    const int bid = blockIdx.x;
    const int ct = bid >> 6;
    const int mt = bid & 63;
    const int c0 = ct << 7, m0 = mt << 7;

    const int tid = threadIdx.x, lane = tid & 63, w = tid >> 6;
    const int wr = (w >> 1) * 64, wc = (w & 1) * 64;
    const int cl = lane & 15, rl = lane >> 4;

    f4v acc[4][4] = {};

    const int lk = tid >> 3;
    const int lg = (tid & 7) * 16;
    const int br = tid >> 2;
    const int bq4 = (tid & 3) * 8;

    for (int k0 = 0; k0 < 512; k0 += 32) {
        {
            const float* g = Wp + (size_t)(k0 + lk) * 512 + c0 + lg;
            #pragma unroll
            for (int u = 0; u < 4; ++u) {
                f4v v = *reinterpret_cast<const f4v*>(g + u * 4);
                unsigned w0 = cvtpk(v[0], v[1]);
                unsigned w1 = cvtpk(v[2], v[3]);
                Al[lg + u * 4 + 0][lk] = (u16)w0;
                Al[lg + u * 4 + 1][lk] = (u16)(w0 >> 16);
                Al[lg + u * 4 + 2][lk] = (u16)w1;
                Al[lg + u * 4 + 3][lk] = (u16)(w1 >> 16);
            }
        }
        #pragma unroll
        for (int it = 0; it < 2; ++it) {
            const int row = br + it * 64;
            s8v v = *reinterpret_cast<const s8v*>(YH + (size_t)(m0 + row) * 512 + k0 + bq4);
            *reinterpret_cast<s8v*>(&Bl[row][bq4]) = v;
        }
        __syncthreads();
        s8v af[4], bfr[4];
        #pragma unroll
        for (int mi = 0; mi < 4; ++mi)
            af[mi] = *reinterpret_cast<const s8v*>(&Al[wr + mi * 16 + cl][rl * 8]);
        #pragma unroll
        for (int ni = 0; ni < 4; ++ni)
            bfr[ni] = *reinterpret_cast<const s8v*>(&Bl[wc + ni * 16 + cl][rl * 8]);
        #pragma unroll
        for (int mi = 0; mi < 4; ++mi)
            #pragma unroll
            for (int ni = 0; ni < 4; ++ni)
                acc[mi][ni] = MFMA(af[mi], bfr[ni], acc[mi][ni]);
        __syncthreads();
    }

    #pragma unroll
    for (int mi = 0; mi < 4; ++mi)
        #pragma unroll
        for (int r = 0; r < 4; ++r) {
            const int c = c0 + wr + mi * 16 + rl * 4 + r;   // D row = cout
            const float bv = bp[c];
            #pragma unroll
            for (int ni = 0; ni < 4; ++ni) {
                const int tok = m0 + wc + ni * 16 + cl;     // D col = token
                const int bb = tok >> 11, t = tok & 2047;
                const int vv = t >> 8, hw = t & 255;
                out[(size_t)(vv * 4 + bb) * 131072 + (size_t)c * 256 + hw] =
                    acc[mi][ni][r] + bv;
            }
        }
}

// ---------------------------------------------------------------------------
extern "C" void kernel_launch(void* const* d_in, const int* in_sizes, int n_in,
                              void* d_out, int out_size, void* d_ws, size_t ws_size,
                              hipStream_t stream)
{
    const float* q   = (const float*)d_in[0];
    const float* kv  = (const float*)d_in[1];
    const float* Wq  = (const float*)d_in[2];
    const float* bq  = (const float*)d_in[3];
    const float* Wkv = (const float*)d_in[4];
    const float* bkv = (const float*)d_in[5];
    const float* Wp  = (const float*)d_in[6];
    const float* bp  = (const float*)d_in[7];
    float* out = (float*)d_out;

    u16* ws = (u16*)d_ws;
    u16* QH = ws;                    // [4][8][2048][64] bf16, prescaled Q
    u16* KH = QH + 4194304;          // [4][8][2048][64]
    u16* VT = KH + 4194304;          // [4][8][64][2048]
    u16* YH = VT + 4194304;          // [4][2048][512]
    u16* Opart = YH + 4194304;       // [1280][128][64] bf16 = 20 MB
    float* ML  = (float*)(Opart + 10485760);  // [1280][128][2] f32 = 1.3 MB

    hipLaunchKernelGGL(qkv_proj, dim3(768), dim3(256), 0, stream,
                       q, kv, Wq, bq, Wkv, bkv, QH, KH, VT);
    hipLaunchKernelGGL(attn_part, dim3(1280), dim3(256), 0, stream,
                       QH, KH, VT, Opart, ML);
    hipLaunchKernelGGL(attn_combine, dim3(512), dim3(256), 0, stream,
                       Opart, ML, YH);
    hipLaunchKernelGGL(out_proj, dim3(256), dim3(256), 0, stream, YH, Wp, bp, out);
}